// Round 1
// baseline (396.014 us; speedup 1.0000x reference)
//
#include <hip/hip_runtime.h>
#include <hip/hip_bf16.h>
#include <math.h>

#define N 2048
#define NC 8

// ws layout:
//   [0, 64)                    : double acc[8]   (column BCE sums, zeroed via memsetAsync)
//   [64, 64+64K)               : float  A[8][2048]
//   [64+64K, 64+128K)          : int    lohi[8][2048]  (lo | hi<<16, per ORIGINAL row index)

// ---------------- Kernel 1: A_sum[j] = sum_i |s_j - s_i| per column ----------------
__global__ __launch_bounds__(256) void k_asum(const float* __restrict__ logits,
                                              float* __restrict__ A) {
    int col = blockIdx.x >> 3;   // 0..7
    int chunk = blockIdx.x & 7;  // 0..7 (256 j's each)
    __shared__ float s[N];
    int tid = threadIdx.x;
    for (int k = 0; k < N / 256; ++k) {
        int i = tid + k * 256;
        s[i] = logits[i * NC + col];
    }
    __syncthreads();
    int j = chunk * 256 + tid;
    float sj = s[j];
    double a0 = 0.0, a1 = 0.0;
    for (int i = 0; i < N; i += 2) {
        a0 += (double)fabsf(sj - s[i]);
        a1 += (double)fabsf(sj - s[i + 1]);
    }
    A[col * N + j] = (float)(a0 + a1);
}

// ---------------- Kernel 2: per-column stable argsort(durations) + GT window ----------------
__global__ __launch_bounds__(256) void k_sortgt(const float* __restrict__ dur,
                                                const int* __restrict__ ev,
                                                int* __restrict__ lohi) {
    int col = blockIdx.x;
    __shared__ unsigned long long keys[N];
    __shared__ int ebuf[N];
    __shared__ int bufA[N];
    __shared__ int bufB[N];
    int tid = threadIdx.x;

    // pack (duration_bits << 32) | index  -> ascending u64 sort == stable ascending by d
    for (int k = 0; k < N / 256; ++k) {
        int i = tid + k * 256;
        float d = dur[i * NC + col];
        keys[i] = ((unsigned long long)__float_as_uint(d) << 32) | (unsigned int)i;
    }
    __syncthreads();

    // bitonic sort, ascending
    for (int k = 2; k <= N; k <<= 1) {
        for (int j2 = k >> 1; j2 > 0; j2 >>= 1) {
            for (int i = tid; i < N; i += 256) {
                int p = i ^ j2;
                if (p > i) {
                    bool up = ((i & k) == 0);
                    unsigned long long x = keys[i], y = keys[p];
                    if ((x > y) == up) { keys[i] = y; keys[p] = x; }
                }
            }
            __syncthreads();
        }
    }

    // events in sorted order
    for (int k = 0; k < N / 256; ++k) {
        int i = tid + k * 256;
        int orig = (int)(keys[i] & 0xffffffffu);
        int e = ev[orig * NC + col];
        ebuf[i] = e;
        bufA[i] = e;
    }
    __syncthreads();

    // inclusive Hillis-Steele scan (ping-pong)
    int* src = bufA;
    int* dst = bufB;
    for (int off = 1; off < N; off <<= 1) {
        for (int k = 0; k < N / 256; ++k) {
            int i = tid + k * 256;
            int v = src[i];
            if (i >= off) v += src[i - off];
            dst[i] = v;
        }
        __syncthreads();
        int* t = src; src = dst; dst = t;
    }

    // lo = exclusive count of events before i; hi = e ? i+1 : N; scatter to original row
    for (int k = 0; k < N / 256; ++k) {
        int i = tid + k * 256;
        int e = ebuf[i];
        int lo = src[i] - e;
        int hi = e ? (i + 1) : N;
        int orig = (int)(keys[i] & 0xffffffffu);
        lohi[col * N + orig] = lo | (hi << 16);
    }
}

// ---------------- Kernel 3: per-row softmax + BCE, 1 wave per row ----------------
__global__ __launch_bounds__(256) void k_bce(const float* __restrict__ logits,
                                             const float* __restrict__ A,
                                             const int* __restrict__ lohi,
                                             double* __restrict__ acc) {
    int col = blockIdx.x >> 9;   // 0..7
    int rg  = blockIdx.x & 511;  // row group of 4
    __shared__ float s[N];
    __shared__ float a[N];
    int tid = threadIdx.x;
    for (int k = 0; k < N / 256; ++k) {
        int i = tid + k * 256;
        s[i] = logits[i * NC + col];
        a[i] = A[col * N + i];
    }
    __syncthreads();

    int wave = tid >> 6;
    int lane = tid & 63;
    int row = rg * 4 + wave;
    float scale = (float)(N - 1 - 2 * row);

    // pass 1: row max of t = scale*s_j - A_j
    float m = -INFINITY;
    for (int j = lane; j < N; j += 64) {
        float t = fmaf(scale, s[j], -a[j]);
        m = fmaxf(m, t);
    }
    #pragma unroll
    for (int off = 32; off > 0; off >>= 1)
        m = fmaxf(m, __shfl_xor(m, off, 64));

    // pass 2: sum exp(t - m)  (f64 accumulate ~= fp32 pairwise to 1 ulp)
    double se = 0.0;
    for (int j = lane; j < N; j += 64) {
        float t = fmaf(scale, s[j], -a[j]);
        se += (double)expf(t - m);
    }
    #pragma unroll
    for (int off = 32; off > 0; off >>= 1)
        se += __shfl_xor(se, off, 64);
    float sumexp = (float)se;

    int lh = lohi[col * N + row];
    int lo = lh & 0xffff;
    int hi = (lh >> 16) & 0xffff;
    float y = 1.0f / (float)(hi - lo);

    // pass 3: BCE terms.  row_sum = sum_j l1mp + y * sum_{j in [lo,hi)} (lp - l1mp)
    double a1 = 0.0, a2 = 0.0;
    for (int j = lane; j < N; j += 64) {
        float t = fmaf(scale, s[j], -a[j]);
        float p = expf(t - m) / sumexp;
        float l1 = fmaxf(log1pf(-p), -100.0f);
        a1 += (double)l1;
        if (j >= lo && j < hi) {
            float lp = fmaxf(logf(p), -100.0f);
            a2 += (double)(lp - l1);
        }
    }
    #pragma unroll
    for (int off = 32; off > 0; off >>= 1) {
        a1 += __shfl_xor(a1, off, 64);
        a2 += __shfl_xor(a2, off, 64);
    }
    if (lane == 0) {
        double rowsum = a1 + (double)y * a2;
        atomicAdd(&acc[col], rowsum);
    }
}

// ---------------- Kernel 4: masked mean over 8 column losses ----------------
__global__ void k_final(const double* __restrict__ acc, float* __restrict__ out) {
    if (threadIdx.x == 0 && blockIdx.x == 0) {
        float ssum = 0.0f;
        int cnt = 0;
        for (int c = 0; c < NC; ++c) {
            float lc = (float)(-acc[c] / ((double)N * (double)N));
            if (lc > 0.0f) { ssum += lc; cnt++; }
        }
        out[0] = ssum / (float)(cnt > 0 ? cnt : 1);
    }
}

extern "C" void kernel_launch(void* const* d_in, const int* in_sizes, int n_in,
                              void* d_out, int out_size, void* d_ws, size_t ws_size,
                              hipStream_t stream) {
    const float* logits    = (const float*)d_in[0];
    const int*   events    = (const int*)d_in[1];
    const float* durations = (const float*)d_in[2];
    float* out = (float*)d_out;

    char* ws = (char*)d_ws;
    double* acc = (double*)ws;
    float*  A    = (float*)(ws + 64);
    int*    lohi = (int*)(ws + 64 + (size_t)NC * N * sizeof(float));

    hipMemsetAsync(acc, 0, NC * sizeof(double), stream);
    k_asum<<<dim3(NC * 8), 256, 0, stream>>>(logits, A);
    k_sortgt<<<dim3(NC), 256, 0, stream>>>(durations, events, lohi);
    k_bce<<<dim3(NC * 512), 256, 0, stream>>>(logits, A, lohi, acc);
    k_final<<<dim3(1), 64, 0, stream>>>(acc, out);
}

// Round 2
// 202.686 us; speedup vs baseline: 1.9538x; 1.9538x over previous
//
#include <hip/hip_runtime.h>
#include <hip/hip_bf16.h>
#include <math.h>

#define N 2048
#define NC 8

// ws layout:
//   [0, 64)          : double acc[8]   (column BCE sums, zeroed via memsetAsync)
//   [64, 64+64K)     : float  A[8][2048]
//   [64+64K, +64K)   : int    lohi[8][2048]  (lo | hi<<16, per ORIGINAL row index)

// ---------------- Kernel 1: A[j] = sum_i |s_j - s_i| per column ----------------
// 8 cols x 32 chunks of 64 j's; 256 threads = 4 i-slices of 512 per j (det. combine)
__global__ __launch_bounds__(256) void k_asum(const float* __restrict__ logits,
                                              float* __restrict__ A) {
    int col   = blockIdx.x >> 5;  // 0..7
    int chunk = blockIdx.x & 31;  // 0..31
    __shared__ float s[N];
    __shared__ double part[256];
    int tid = threadIdx.x;
    for (int k = 0; k < N / 256; ++k) {
        int i = tid + k * 256;
        s[i] = logits[i * NC + col];
    }
    __syncthreads();
    int jl = tid & 63, slice = tid >> 6;
    int j = chunk * 64 + jl;
    float sj = s[j];
    int base = slice * 512;
    double a0 = 0.0, a1 = 0.0;
    #pragma unroll 4
    for (int i = 0; i < 512; i += 2) {
        a0 += (double)fabsf(sj - s[base + i]);
        a1 += (double)fabsf(sj - s[base + i + 1]);
    }
    part[tid] = a0 + a1;
    __syncthreads();
    if (tid < 64) {
        double v = ((part[tid] + part[tid + 64]) + part[tid + 128]) + part[tid + 192];
        A[col * N + j] = (float)v;
    }
}

// ---------------- Kernel 2: counting-rank GT windows (no sort, no scan) -------
// key = (dur_bits<<32)|(i<<1)|e : ascending u64 order == stable ascending by d
// rank_j = #{key_i < key_j}; lo = #{key_i < key_j and e_i=1}; hi = e ? rank+1 : N
__global__ __launch_bounds__(256) void k_sortgt(const float* __restrict__ dur,
                                                const int* __restrict__ ev,
                                                int* __restrict__ lohi) {
    int col   = blockIdx.x >> 4;  // 0..7
    int chunk = blockIdx.x & 15;  // 16 chunks x 128 j
    __shared__ unsigned long long keys[N];  // 16 KB
    __shared__ int pr[256], pv[256];
    int tid = threadIdx.x;
    for (int k = 0; k < N / 256; ++k) {
        int i = tid + k * 256;
        unsigned int db = __float_as_uint(dur[i * NC + col]);  // dur in [0,1): bit order == float order
        int e = ev[i * NC + col];
        keys[i] = ((unsigned long long)db << 32) | (unsigned int)((i << 1) | e);
    }
    __syncthreads();
    int jl = tid & 127, half = tid >> 7;
    int j = chunk * 128 + jl;
    unsigned long long kj = keys[j];
    int base = half * 1024;
    int rank = 0, evlt = 0;
    #pragma unroll 4
    for (int i = 0; i < 1024; ++i) {
        unsigned long long ki = keys[base + i];
        int lt = (ki < kj) ? 1 : 0;
        rank += lt;
        evlt += lt & (int)(ki & 1ull);
    }
    pr[tid] = rank;
    pv[tid] = evlt;
    __syncthreads();
    if (half == 0) {
        int r = rank + pr[tid + 128];
        int v = evlt + pv[tid + 128];
        int e = (int)(kj & 1ull);
        int hi = e ? (r + 1) : N;
        lohi[col * N + j] = v | (hi << 16);
    }
}

// ---------------- Kernel 3: per-row softmax + BCE, 1 wave/row, 2 rows/wave ----
// log p_j      = (t_j - m) - L                      (no logf, no div)
// log1p(-p_j)  = log(S - e_j) - L                   (one v_log_f32)
__global__ __launch_bounds__(256) void k_bce(const float* __restrict__ logits,
                                             const float* __restrict__ A,
                                             const int* __restrict__ lohi,
                                             double* __restrict__ acc) {
    int col = blockIdx.x >> 8;   // 0..7
    int rg  = blockIdx.x & 255;  // 0..255 (8 rows each)
    __shared__ float2 sa[N];     // {s_j, A_j} interleaved -> ds_read_b64
    int tid = threadIdx.x;
    for (int k = 0; k < N / 256; ++k) {
        int i = tid + k * 256;
        sa[i] = make_float2(logits[i * NC + col], A[col * N + i]);
    }
    __syncthreads();

    int wave = tid >> 6, lane = tid & 63;
    double rsum = 0.0;

    for (int rep = 0; rep < 2; ++rep) {
        int row = rg * 8 + wave * 2 + rep;
        float scale = (float)(N - 1 - 2 * row);

        // pass 1: t_j = scale*s_j - A_j (cached), row max
        float t[32];
        float m = -INFINITY;
        #pragma unroll
        for (int k = 0; k < 32; ++k) {
            float2 v = sa[lane + k * 64];
            t[k] = fmaf(scale, v.x, -v.y);
            m = fmaxf(m, t[k]);
        }
        #pragma unroll
        for (int off = 32; off > 0; off >>= 1)
            m = fmaxf(m, __shfl_xor(m, off, 64));

        // pass 2: e_j = exp(t_j - m) (cached), S = sum e_j (f64)
        float e[32];
        double se = 0.0;
        #pragma unroll
        for (int k = 0; k < 32; ++k) {
            e[k] = __expf(t[k] - m);
            se += (double)e[k];
        }
        #pragma unroll
        for (int off = 32; off > 0; off >>= 1)
            se += __shfl_xor(se, off, 64);
        float S = (float)se;
        float L = __logf(S);

        int lh = lohi[col * N + row];
        int lo = lh & 0xffff, hi = (lh >> 16) & 0xffff;

        // pass 3: a1 = sum_j l1mp; a2 = sum_window (lp - l1mp)
        double a1 = 0.0, a2 = 0.0;
        #pragma unroll
        for (int k = 0; k < 32; ++k) {
            int j = lane + k * 64;
            float d  = fmaxf(S - e[k], 0.0f);              // log(0) -> -inf -> clamp
            float l1 = fmaxf(__logf(d) - L, -100.0f);
            a1 += (double)l1;
            float lp = fmaxf((t[k] - m) - L, -100.0f);
            bool sel = (j >= lo) && (j < hi);
            a2 += sel ? (double)(lp - l1) : 0.0;
        }
        #pragma unroll
        for (int off = 32; off > 0; off >>= 1) {
            a1 += __shfl_xor(a1, off, 64);
            a2 += __shfl_xor(a2, off, 64);
        }
        float y = 1.0f / (float)(hi - lo);
        rsum += a1 + (double)y * a2;
    }
    if (lane == 0) atomicAdd(&acc[col], rsum);
}

// ---------------- Kernel 4: masked mean over 8 column losses ----------------
__global__ void k_final(const double* __restrict__ acc, float* __restrict__ out) {
    if (threadIdx.x == 0 && blockIdx.x == 0) {
        float ssum = 0.0f;
        int cnt = 0;
        for (int c = 0; c < NC; ++c) {
            float lc = (float)(-acc[c] / ((double)N * (double)N));
            if (lc > 0.0f) { ssum += lc; cnt++; }
        }
        out[0] = ssum / (float)(cnt > 0 ? cnt : 1);
    }
}

extern "C" void kernel_launch(void* const* d_in, const int* in_sizes, int n_in,
                              void* d_out, int out_size, void* d_ws, size_t ws_size,
                              hipStream_t stream) {
    const float* logits    = (const float*)d_in[0];
    const int*   events    = (const int*)d_in[1];
    const float* durations = (const float*)d_in[2];
    float* out = (float*)d_out;

    char* ws = (char*)d_ws;
    double* acc  = (double*)ws;
    float*  A    = (float*)(ws + 64);
    int*    lohi = (int*)(ws + 64 + (size_t)NC * N * sizeof(float));

    hipMemsetAsync(acc, 0, NC * sizeof(double), stream);
    k_asum<<<dim3(NC * 32), 256, 0, stream>>>(logits, A);
    k_sortgt<<<dim3(NC * 16), 256, 0, stream>>>(durations, events, lohi);
    k_bce<<<dim3(NC * 256), 256, 0, stream>>>(logits, A, lohi, acc);
    k_final<<<dim3(1), 64, 0, stream>>>(acc, out);
}